// Round 16
// baseline (245.402 us; speedup 1.0000x reference)
//
#include <hip/hip_runtime.h>

#define NEGSLOPE 0.2f
#define NINF (-3.4e38f)

typedef _Float16 half8 __attribute__((ext_vector_type(8)));
typedef float f32x4 __attribute__((ext_vector_type(4)));
typedef unsigned long long u64;

#define YSTRIDE 72  // f16 units; row stride 144 B (16B-aligned for b128)

__device__ __forceinline__ half8 h8zero() {
    half8 z;
#pragma unroll
    for (int i = 0; i < 8; ++i) z[i] = (_Float16)0.f;
    return z;
}

__device__ __forceinline__ unsigned umin(unsigned a, unsigned b) { return a < b ? a : b; }
__device__ __forceinline__ unsigned umax(unsigned a, unsigned b) { return a > b ? a : b; }

template <int CTRL>
__device__ __forceinline__ unsigned dpp_movm(unsigned v) {
    return (unsigned)__builtin_amdgcn_update_dpp(-1, (int)v, CTRL, 0xF, 0xF, false);
}

// ---------------------------------------------------------------------------
// prep: w1g (W1 -> f16 B-frag order) + w0f (W0 rows zero-padded to half8).
// xt dropped entirely (R15 lesson: producer-written arrays read at scale pay
// cross-XCD dirty-line latency; read pristine x instead).
// ---------------------------------------------------------------------------
__global__ __launch_bounds__(256) void prep_kernel(
    const float* __restrict__ w1, _Float16* __restrict__ w1g,
    const float* __restrict__ w0, _Float16* __restrict__ w0f) {
    const int pid = blockIdx.x;   // 0..7
    int tid = pid * 256 + threadIdx.x;
#pragma unroll
    for (int it = 0; it < 12; ++it, tid += 2048) {
        int j = tid & 7;
        int L = (tid >> 3) & 63;
        int r = tid >> 9;          // r = ks*4 + t4
        int t4 = r & 3;
        int ks = r >> 2;
        int q = L >> 4, c = L & 15;
        int i = ks >> 1;
        int o = 32 * (ks & 1) + 8 * q + j;
        int u = 16 * t4 + c;
        w1g[tid] = (_Float16)w1[(u * 6 + i) * 64 + o];
    }
    if (pid == 0) {
#pragma unroll
        for (int s = 0; s < 2; ++s) {
            int t2 = threadIdx.x * 2 + s;
            int r8 = t2 >> 3, j = t2 & 7;
            w0f[t2] = (j < 6) ? (_Float16)w0[r8 * 6 + j] : (_Float16)0.f;
        }
    }
}

// ---------------------------------------------------------------------------
// fused: per wave -- phase 1: R14 bitonic top-20 (x-plane reads, bit-
// identical keys) for its own 4 points, winners -> wave-private LDS iw[80]
// (no barrier; in-wave lgkmcnt). Phase 2: R14 mlp (y-stage MFMA, swizzled
// y tile, K=384 GEMM2) with e-stage reading pristine x planes (xt gone).
// Fusion is register-safe now (bitonic keeps ~6 persistent VGPRs vs R6's
// skh[32] that spilled).
// ---------------------------------------------------------------------------
__global__ __launch_bounds__(128, 3) void fused_kernel(
    const float* __restrict__ x,
    const _Float16* __restrict__ w0f, const float* __restrict__ bn0s,
    const float* __restrict__ bn0b, const _Float16* __restrict__ w1g,
    const float* __restrict__ bn1s, const float* __restrict__ bn1b,
    const float* __restrict__ wc, const float* __restrict__ bncs,
    const float* __restrict__ bncb, float* __restrict__ out) {
    __shared__ __align__(16) _Float16 yL[2][80 * YSTRIDE];
    __shared__ __align__(16) half8 eL[2][80];
    __shared__ int iwL[2][80];
    const int wave = threadIdx.x >> 6;
    const int lane = threadIdx.x & 63;
    const int q = lane >> 4, c = lane & 15;
    const int gw = blockIdx.x * 2 + wave;     // 0..4095
    const int b = gw >> 9;                    // 512 waves per batch
    const int P0 = (gw & 511) * 4;
    const float* xb = x + b * 6144;
    _Float16* yw = yL[wave];
    half8* ew = eL[wave];
    int* iw = iwL[wave];

    // ==================== phase 1: bitonic top-20 x4 rows ====================
#define CROSS(DL, KK)                                                         \
    {                                                                         \
        const bool asc = ((lane >> ((KK) - 2)) & 1) == 0;                     \
        const bool low = (lane & (DL)) == 0;                                  \
        const bool selmin = (asc == low);                                     \
        const unsigned p0 = (unsigned)__shfl_xor((int)r0, (DL), 64);          \
        const unsigned p1 = (unsigned)__shfl_xor((int)r1, (DL), 64);          \
        const unsigned p2 = (unsigned)__shfl_xor((int)r2, (DL), 64);          \
        const unsigned p3 = (unsigned)__shfl_xor((int)r3, (DL), 64);          \
        r0 = selmin ? umin(r0, p0) : umax(r0, p0);                            \
        r1 = selmin ? umin(r1, p1) : umax(r1, p1);                            \
        r2 = selmin ? umin(r2, p2) : umax(r2, p2);                            \
        r3 = selmin ? umin(r3, p3) : umax(r3, p3);                            \
    }
#define INLANE(KK)                                                            \
    {                                                                         \
        const bool asc = ((lane >> ((KK) - 2)) & 1) == 0;                     \
        { unsigned lo = umin(r0, r2), hi = umax(r0, r2);                      \
          r0 = asc ? lo : hi; r2 = asc ? hi : lo; }                           \
        { unsigned lo = umin(r1, r3), hi = umax(r1, r3);                      \
          r1 = asc ? lo : hi; r3 = asc ? hi : lo; }                           \
        { unsigned lo = umin(r0, r1), hi = umax(r0, r1);                      \
          r0 = asc ? lo : hi; r1 = asc ? hi : lo; }                           \
        { unsigned lo = umin(r2, r3), hi = umax(r2, r3);                      \
          r2 = asc ? lo : hi; r3 = asc ? hi : lo; }                           \
    }

#pragma unroll 1
    for (int rr = 0; rr < 4; ++rr) {
        const int n = P0 + rr;
        const float xn0 = xb[n];
        const float xn1 = xb[2048 + n];
        const float xn2 = xb[4096 + n];

        unsigned r0 = 0xFFFFFFFFu, r1 = 0xFFFFFFFFu;
        unsigned r2 = 0xFFFFFFFFu, r3 = 0xFFFFFFFFu;   // per-lane top-4
        unsigned g5k = 0xFFFFFFFFu;                    // 5th-smallest guard

#pragma unroll
        for (int t = 0; t < 32; ++t) {
            const int j = t * 64 + lane;
            const float dx = xb[j] - xn0;
            const float dy = xb[2048 + j] - xn1;
            const float dz = xb[4096 + j] - xn2;
            const float d = dx * dx + dy * dy + dz * dz;
            unsigned p = (__float_as_uint(d) & 0xFFFFF800u) | (unsigned)j;
            unsigned q0 = umin(r0, p); p = umax(r0, p); r0 = q0;
            unsigned q1 = umin(r1, p); p = umax(r1, p); r1 = q1;
            unsigned q2 = umin(r2, p); p = umax(r2, p); r2 = q2;
            unsigned q3 = umin(r3, p); p = umax(r3, p); r3 = q3;
            g5k = umin(g5k, p);
        }

        // bitonic sort of 256 (i = 4*lane + slot), stages 1-2 free
        if (lane & 1) {
            unsigned t0 = r0; r0 = r3; r3 = t0;
            unsigned t1 = r1; r1 = r2; r2 = t1;
        }
        CROSS(1, 3)  INLANE(3)
        CROSS(2, 4)  CROSS(1, 4)  INLANE(4)
        CROSS(4, 5)  CROSS(2, 5)  CROSS(1, 5)  INLANE(5)
        CROSS(8, 6)  CROSS(4, 6)  CROSS(2, 6)  CROSS(1, 6)  INLANE(6)
        CROSS(16, 7) CROSS(8, 7)  CROSS(4, 7)  CROSS(2, 7)  CROSS(1, 7)  INLANE(7)
        CROSS(32, 8) CROSS(16, 8) CROSS(8, 8)  CROSS(4, 8)  CROSS(2, 8)
        CROSS(1, 8)  INLANE(8)

        const unsigned T20p = (unsigned)__builtin_amdgcn_readlane((int)r3, 4);
        const u64 bad = __ballot(g5k < T20p);

        if (bad == 0) {
            if (lane < 5) {   // ranks 4*lane..4*lane+3 -> iw[k*4+rr]
                iw[(4 * lane + 0) * 4 + rr] = (int)(r0 & 2047u);
                iw[(4 * lane + 1) * 4 + rr] = (int)(r1 & 2047u);
                iw[(4 * lane + 2) * 4 + rr] = (int)(r2 & 2047u);
                iw[(4 * lane + 3) * 4 + rr] = (int)(r3 & 2047u);
            }
        } else {
            // exact fallback (rare ~0.1%/row): 20 rounds of recompute+min
            unsigned Tprev = 0u;
#pragma unroll 1
            for (int rk = 0; rk < 20; ++rk) {
                unsigned best = 0xFFFFFFFFu;
#pragma unroll
                for (int t = 0; t < 32; ++t) {
                    const int j = t * 64 + lane;
                    const float dx = xb[j] - xn0;
                    const float dy = xb[2048 + j] - xn1;
                    const float dz = xb[4096 + j] - xn2;
                    const float d = dx * dx + dy * dy + dz * dz;
                    const unsigned p =
                        (__float_as_uint(d) & 0xFFFFF800u) | (unsigned)j;
                    const bool ok = (rk == 0) || (p > Tprev);
                    best = umin(best, ok ? p : 0xFFFFFFFFu);
                }
                { unsigned o = dpp_movm<0x111>(best); best = umin(best, o); }
                { unsigned o = dpp_movm<0x112>(best); best = umin(best, o); }
                { unsigned o = dpp_movm<0x114>(best); best = umin(best, o); }
                { unsigned o = dpp_movm<0x118>(best); best = umin(best, o); }
                { unsigned o = dpp_movm<0x142>(best); best = umin(best, o); }
                { unsigned o = dpp_movm<0x143>(best); best = umin(best, o); }
                const unsigned K =
                    (unsigned)__builtin_amdgcn_readlane((int)best, 63);
                if (lane == 0) iw[rk * 4 + rr] = (int)(K & 2047u);
                Tprev = K;
            }
        }
    }
#undef CROSS
#undef INLANE

    // ==================== phase 2: edge MLP + GEMMs (R14 mlp) ====================
    // e-stage: lane <-> edge (and +64 for lanes<16); x-plane reads, iw from LDS
    {
        const int pt = lane & 3;
        const int n = P0 + pt;
        const int j = iw[lane];
        const float c0 = xb[n], c1 = xb[2048 + n], c2 = xb[4096 + n];
        half8 ev;
        ev[0] = (_Float16)(xb[j] - c0);
        ev[1] = (_Float16)(xb[2048 + j] - c1);
        ev[2] = (_Float16)(xb[4096 + j] - c2);
        ev[3] = (_Float16)c0; ev[4] = (_Float16)c1; ev[5] = (_Float16)c2;
        ev[6] = (_Float16)0.f; ev[7] = (_Float16)0.f;
        ew[lane] = ev;
    }
    if (lane < 16) {
        const int el = 64 + lane;
        const int pt = el & 3;
        const int n = P0 + pt;
        const int j = iw[el];
        const float c0 = xb[n], c1 = xb[2048 + n], c2 = xb[4096 + n];
        half8 ev;
        ev[0] = (_Float16)(xb[j] - c0);
        ev[1] = (_Float16)(xb[2048 + j] - c1);
        ev[2] = (_Float16)(xb[4096 + j] - c2);
        ev[3] = (_Float16)c0; ev[4] = (_Float16)c1; ev[5] = (_Float16)c2;
        ev[6] = (_Float16)0.f; ev[7] = (_Float16)0.f;
        ew[el] = ev;
    }

    // y-stage via MFMA: y_raw = e @ W0^T, bn0+leaky, swizzled scatter
    const half8* w0f8 = (const half8*)w0f;
    const half8 z8 = h8zero();
    half8 B1[4];
    float s0v[4], b0v[4];
#pragma unroll
    for (int nt = 0; nt < 4; ++nt) {
        const half8 v = w0f8[nt * 16 + c];
        B1[nt] = (q == 0) ? v : z8;
        s0v[nt] = bn0s[16 * nt + c];
        b0v[nt] = bn0b[16 * nt + c];
    }
#pragma unroll
    for (int mt = 0; mt < 5; ++mt) {
        const half8 ev = ew[16 * mt + c];
        const half8 Ae = (q == 0) ? ev : z8;
        const int ebase = 16 * mt + 4 * q;
#pragma unroll
        for (int nt = 0; nt < 4; ++nt) {
            f32x4 D = {0.f, 0.f, 0.f, 0.f};
            D = __builtin_amdgcn_mfma_f32_16x16x32_f16(Ae, B1[nt], D, 0, 0, 0);
#pragma unroll
            for (int r = 0; r < 4; ++r) {
                float v = D[r] * s0v[nt] + b0v[nt];
                v = fmaxf(v, NEGSLOPE * v);
                const int edge = ebase + r;
                yw[edge * YSTRIDE + ((16 * nt + c) ^ (edge & 0x38))] =
                    (_Float16)v;
            }
        }
    }

    // GEMM2: K=384, acc chained through MFMA C
    const half8* w1g8 = (const half8*)w1g;

    f32x4 acc[5][4];  // [m][t4], u = 16*t4 + c, edge row = 4q + r
#pragma unroll
    for (int mm = 0; mm < 5; ++mm)
#pragma unroll
        for (int t4 = 0; t4 < 4; ++t4) acc[mm][t4] = (f32x4){0.f, 0.f, 0.f, 0.f};

#pragma unroll 1
    for (int i6 = 0; i6 < 6; ++i6) {
        _Float16 es[5];
#pragma unroll
        for (int mm = 0; mm < 5; ++mm)
            es[mm] = ((const _Float16*)(ew + 16 * mm + c))[i6];
#pragma unroll
        for (int ks2 = 0; ks2 < 2; ++ks2) {
            const int ks = 2 * i6 + ks2;
            half8 B[4];
#pragma unroll
            for (int t4 = 0; t4 < 4; ++t4)
                B[t4] = w1g8[(ks * 4 + t4) * 64 + lane];
#pragma unroll
            for (int mm = 0; mm < 5; ++mm) {
                const int rrow = 16 * mm + c;
                const half8 Af = *(const half8*)&yw[rrow * YSTRIDE +
                                                    ((32 * ks2 + 8 * q) ^ (rrow & 0x38))];
                const half8 An = Af * es[mm];
#pragma unroll
                for (int t4 = 0; t4 < 4; ++t4)
                    acc[mm][t4] = __builtin_amdgcn_mfma_f32_16x16x32_f16(
                        An, B[t4], acc[mm][t4], 0, 0, 0);
            }
        }
    }

    // bn1 + leaky + max over k (k = 4m+q)
    float bs1[4], bb1[4];
#pragma unroll
    for (int t4 = 0; t4 < 4; ++t4) {
        bs1[t4] = bn1s[16 * t4 + c];
        bb1[t4] = bn1b[16 * t4 + c];
    }

    float x1[4][4];  // [pt r][t4]
#pragma unroll
    for (int r = 0; r < 4; ++r)
#pragma unroll
        for (int t4 = 0; t4 < 4; ++t4) {
            float v = NINF;
#pragma unroll
            for (int mm = 0; mm < 5; ++mm) {
                float w = acc[mm][t4][r] * bs1[t4] + bb1[t4];
                w = fmaxf(w, NEGSLOPE * w);
                v = fmaxf(v, w);
            }
            v = fmaxf(v, __shfl_xor(v, 16, 64));
            v = fmaxf(v, __shfl_xor(v, 32, 64));
            x1[r][t4] = v;
        }

    // head: z[pt][co] = leaky(bnc(sum_u x1*wc))
    float wcv[3][4];
#pragma unroll
    for (int co = 0; co < 3; ++co)
#pragma unroll
        for (int t4 = 0; t4 < 4; ++t4) wcv[co][t4] = wc[co * 64 + 16 * t4 + c];

    float part[4][3];
#pragma unroll
    for (int r = 0; r < 4; ++r)
#pragma unroll
        for (int co = 0; co < 3; ++co) {
            float s = x1[r][0] * wcv[co][0] + x1[r][1] * wcv[co][1] +
                      x1[r][2] * wcv[co][2] + x1[r][3] * wcv[co][3];
#pragma unroll
            for (int d = 1; d < 16; d <<= 1) s += __shfl_xor(s, d, 64);
            part[r][co] = s;
        }

    if (c == 0 && q < 3) {
        const float sc = bncs[q], bc = bncb[q];
#pragma unroll
        for (int r = 0; r < 4; ++r) {
            float z = part[r][q] * sc + bc;
            z = fmaxf(z, NEGSLOPE * z);
            out[(b * 3 + q) * 2048 + P0 + r] = z;
        }
    }
}

// ---------------------------------------------------------------------------
extern "C" void kernel_launch(void* const* d_in, const int* in_sizes, int n_in,
                              void* d_out, int out_size, void* d_ws, size_t ws_size,
                              hipStream_t stream) {
    const float* x    = (const float*)d_in[0];
    const float* W0   = (const float*)d_in[1];
    const float* bn0s = (const float*)d_in[2];
    const float* bn0b = (const float*)d_in[3];
    const float* W1   = (const float*)d_in[4];
    const float* bn1s = (const float*)d_in[5];
    const float* bn1b = (const float*)d_in[6];
    const float* Wc   = (const float*)d_in[7];
    const float* bncs = (const float*)d_in[8];
    const float* bncb = (const float*)d_in[9];

    _Float16* w1g = (_Float16*)d_ws;                     // 48 KiB @ 0
    _Float16* w0f = (_Float16*)((char*)d_ws + 49152);    // 1 KiB

    prep_kernel<<<8, 256, 0, stream>>>(W1, w1g, W0, w0f);
    fused_kernel<<<2048, 128, 0, stream>>>(x, w0f, bn0s, bn0b, w1g,
                                           bn1s, bn1b, Wc, bncs, bncb,
                                           (float*)d_out);
}

// Round 17
// 143.065 us; speedup vs baseline: 1.7153x; 1.7153x over previous
//
#include <hip/hip_runtime.h>

#define NEGSLOPE 0.2f
#define NINF (-3.4e38f)

typedef _Float16 half8 __attribute__((ext_vector_type(8)));
typedef float f32x4 __attribute__((ext_vector_type(4)));
typedef unsigned long long u64;

#define YSTRIDE 72  // f16 units; row stride 144 B (16B-aligned for b128)

__device__ __forceinline__ half8 h8zero() {
    half8 z;
#pragma unroll
    for (int i = 0; i < 8; ++i) z[i] = (_Float16)0.f;
    return z;
}

__device__ __forceinline__ unsigned umin(unsigned a, unsigned b) { return a < b ? a : b; }
__device__ __forceinline__ unsigned umax(unsigned a, unsigned b) { return a > b ? a : b; }

template <int CTRL>
__device__ __forceinline__ unsigned dpp_movm(unsigned v) {
    return (unsigned)__builtin_amdgcn_update_dpp(-1, (int)v, CTRL, 0xF, 0xF, false);
}

// ---------------------------------------------------------------------------
// topk v14 (R14 bitonic, x-fed -- unchanged selection) + folded prep.
// Blocks >= 4096 (pid 0..7): pid writes w1g COPY pid (8 replicas, so mlp
// block i reads copy i&7 -> same-XCD L2 under the round-robin block->XCD
// heuristic; avoids R15's cross-XCD dirty-line penalty). pid 0 also w0f.
// xt is DELETED (R15 lesson: scale reads of producer-written arrays pay
// cross-XCD latency; pristine x is cheap).
// ---------------------------------------------------------------------------
__global__ __launch_bounds__(256) void topk_kernel(
    const float* __restrict__ x, int* __restrict__ idx_out,
    const float* __restrict__ w1, _Float16* __restrict__ w1g,
    const float* __restrict__ w0, _Float16* __restrict__ w0f) {
    if (blockIdx.x >= 4096) {
        const int pid = blockIdx.x - 4096;   // 0..7
        _Float16* dst = w1g + pid * 24576;
        for (int e = threadIdx.x; e < 24576; e += 256) {
            int j = e & 7;
            int L = (e >> 3) & 63;
            int r = e >> 9;            // r = ks*4 + t4
            int t4 = r & 3;
            int ks = r >> 2;
            int q = L >> 4, c = L & 15;
            int i = ks >> 1;
            int o = 32 * (ks & 1) + 8 * q + j;
            int u = 16 * t4 + c;
            dst[e] = (_Float16)w1[(u * 6 + i) * 64 + o];
        }
        if (pid == 0) {
#pragma unroll
            for (int s = 0; s < 2; ++s) {
                int t2 = threadIdx.x * 2 + s;
                int r8 = t2 >> 3, j = t2 & 7;
                w0f[t2] = (j < 6) ? (_Float16)w0[r8 * 6 + j] : (_Float16)0.f;
            }
        }
        return;
    }

    const int wave = threadIdx.x >> 6;
    const int lane = threadIdx.x & 63;
    const int row = blockIdx.x * 4 + wave;
    const int b = row >> 11;
    const int n = row & 2047;
    const float* xb = x + b * 6144;
    const float xn0 = xb[n];
    const float xn1 = xb[2048 + n];
    const float xn2 = xb[4096 + n];

    unsigned r0 = 0xFFFFFFFFu, r1 = 0xFFFFFFFFu;
    unsigned r2 = 0xFFFFFFFFu, r3 = 0xFFFFFFFFu;   // per-lane top-4, sorted
    unsigned g5k = 0xFFFFFFFFu;                    // per-lane 5th-smallest

#pragma unroll
    for (int t = 0; t < 32; ++t) {
        const int j = t * 64 + lane;
        const float dx = xb[j] - xn0;
        const float dy = xb[2048 + j] - xn1;
        const float dz = xb[4096 + j] - xn2;
        const float d = dx * dx + dy * dy + dz * dz;
        unsigned p = (__float_as_uint(d) & 0xFFFFF800u) | (unsigned)j;
        // branchless sorted insert (drop largest into g5k)
        unsigned q0 = umin(r0, p); p = umax(r0, p); r0 = q0;
        unsigned q1 = umin(r1, p); p = umax(r1, p); r1 = q1;
        unsigned q2 = umin(r2, p); p = umax(r2, p); r2 = q2;
        unsigned q3 = umin(r3, p); p = umax(r3, p); r3 = q3;
        g5k = umin(g5k, p);
    }

    // ---- bitonic sort of 256 (i = 4*lane + slot), stages 1-2 free ----
    if (lane & 1) {  // odd lanes: reverse to descending
        unsigned t0 = r0; r0 = r3; r3 = t0;
        unsigned t1 = r1; r1 = r2; r2 = t1;
    }

#define CROSS(DL, KK)                                                         \
    {                                                                         \
        const bool asc = ((lane >> ((KK) - 2)) & 1) == 0;                     \
        const bool low = (lane & (DL)) == 0;                                  \
        const bool selmin = (asc == low);                                     \
        const unsigned p0 = (unsigned)__shfl_xor((int)r0, (DL), 64);          \
        const unsigned p1 = (unsigned)__shfl_xor((int)r1, (DL), 64);          \
        const unsigned p2 = (unsigned)__shfl_xor((int)r2, (DL), 64);          \
        const unsigned p3 = (unsigned)__shfl_xor((int)r3, (DL), 64);          \
        r0 = selmin ? umin(r0, p0) : umax(r0, p0);                            \
        r1 = selmin ? umin(r1, p1) : umax(r1, p1);                            \
        r2 = selmin ? umin(r2, p2) : umax(r2, p2);                            \
        r3 = selmin ? umin(r3, p3) : umax(r3, p3);                            \
    }
#define INLANE(KK)                                                            \
    {                                                                         \
        const bool asc = ((lane >> ((KK) - 2)) & 1) == 0;                     \
        { unsigned lo = umin(r0, r2), hi = umax(r0, r2);                      \
          r0 = asc ? lo : hi; r2 = asc ? hi : lo; }                           \
        { unsigned lo = umin(r1, r3), hi = umax(r1, r3);                      \
          r1 = asc ? lo : hi; r3 = asc ? hi : lo; }                           \
        { unsigned lo = umin(r0, r1), hi = umax(r0, r1);                      \
          r0 = asc ? lo : hi; r1 = asc ? hi : lo; }                           \
        { unsigned lo = umin(r2, r3), hi = umax(r2, r3);                      \
          r2 = asc ? lo : hi; r3 = asc ? hi : lo; }                           \
    }

    CROSS(1, 3)  INLANE(3)
    CROSS(2, 4)  CROSS(1, 4)  INLANE(4)
    CROSS(4, 5)  CROSS(2, 5)  CROSS(1, 5)  INLANE(5)
    CROSS(8, 6)  CROSS(4, 6)  CROSS(2, 6)  CROSS(1, 6)  INLANE(6)
    CROSS(16, 7) CROSS(8, 7)  CROSS(4, 7)  CROSS(2, 7)  CROSS(1, 7)  INLANE(7)
    CROSS(32, 8) CROSS(16, 8) CROSS(8, 8)  CROSS(4, 8)  CROSS(2, 8)  CROSS(1, 8)
    INLANE(8)
#undef CROSS
#undef INLANE

    const int out_base = row * 20;
    // kept 20th-smallest = position 19 = lane 4, slot 3
    const unsigned T20p = (unsigned)__builtin_amdgcn_readlane((int)r3, 4);
    const u64 bad = __ballot(g5k < T20p);

    if (bad == 0) {
        if (lane < 5) {
            int4 v;
            v.x = (int)(r0 & 2047u); v.y = (int)(r1 & 2047u);
            v.z = (int)(r2 & 2047u); v.w = (int)(r3 & 2047u);
            *(int4*)(idx_out + out_base + lane * 4) = v;
        }
    } else {
        // exact fallback (rare, ~0.1% of rows): 20 rounds of recompute+min
        unsigned Tprev = 0u;
#pragma unroll 1
        for (int r = 0; r < 20; ++r) {
            unsigned best = 0xFFFFFFFFu;
#pragma unroll
            for (int t = 0; t < 32; ++t) {
                const int j = t * 64 + lane;
                const float dx = xb[j] - xn0;
                const float dy = xb[2048 + j] - xn1;
                const float dz = xb[4096 + j] - xn2;
                const float d = dx * dx + dy * dy + dz * dz;
                const unsigned p = (__float_as_uint(d) & 0xFFFFF800u) | (unsigned)j;
                const bool ok = (r == 0) || (p > Tprev);
                best = umin(best, ok ? p : 0xFFFFFFFFu);
            }
            { unsigned o = dpp_movm<0x111>(best); best = umin(best, o); }
            { unsigned o = dpp_movm<0x112>(best); best = umin(best, o); }
            { unsigned o = dpp_movm<0x114>(best); best = umin(best, o); }
            { unsigned o = dpp_movm<0x118>(best); best = umin(best, o); }
            { unsigned o = dpp_movm<0x142>(best); best = umin(best, o); }
            { unsigned o = dpp_movm<0x143>(best); best = umin(best, o); }
            const unsigned K = (unsigned)__builtin_amdgcn_readlane((int)best, 63);
            if (lane == 0) idx_out[out_base + r] = (int)(K & 2047u);
            Tprev = K;
        }
    }
}

// ---------------------------------------------------------------------------
// mlp v5: R14 structure with two dirty-line fixes: (1) e-stage gathers read
// pristine x planes (xt deleted); (2) GEMM2 B-frags read the w1g replica
// selected by blockIdx&7 (round-robin XCD heuristic -> local-L2 hits).
// y-stage MFMA, swizzled y tile, K=384 GEMM2, no barrier -- all unchanged.
// ---------------------------------------------------------------------------
__global__ __launch_bounds__(128, 3) void mlp_mfma(
    const float* __restrict__ x, const int* __restrict__ idx,
    const _Float16* __restrict__ w0f, const float* __restrict__ bn0s,
    const float* __restrict__ bn0b, const _Float16* __restrict__ w1g,
    const float* __restrict__ bn1s, const float* __restrict__ bn1b,
    const float* __restrict__ wc, const float* __restrict__ bncs,
    const float* __restrict__ bncb, float* __restrict__ out) {
    __shared__ __align__(16) _Float16 yL[2][80 * YSTRIDE];
    __shared__ __align__(16) half8 eL[2][80];
    const int wave = threadIdx.x >> 6;
    const int lane = threadIdx.x & 63;
    const int q = lane >> 4, c = lane & 15;
    const int gw = blockIdx.x * 2 + wave;     // 0..4095
    const int b = gw >> 9;                    // 512 waves per batch
    const int P0 = (gw & 511) * 4;
    _Float16* yw = yL[wave];
    half8* ew = eL[wave];
    const float* xb = x + b * 6144;

    // ---- e-stage: pristine x-plane gathers (6 dwords per edge) ----
    {
        const int k = lane >> 2, pt = lane & 3;
        const int n = P0 + pt;
        const int j = idx[(b * 2048 + n) * 20 + k];
        const float c0 = xb[n], c1 = xb[2048 + n], c2 = xb[4096 + n];
        half8 ev;
        ev[0] = (_Float16)(xb[j] - c0);
        ev[1] = (_Float16)(xb[2048 + j] - c1);
        ev[2] = (_Float16)(xb[4096 + j] - c2);
        ev[3] = (_Float16)c0; ev[4] = (_Float16)c1; ev[5] = (_Float16)c2;
        ev[6] = (_Float16)0.f; ev[7] = (_Float16)0.f;
        ew[lane] = ev;
    }
    if (lane < 16) {
        const int el = 64 + lane;
        const int k = el >> 2, pt = el & 3;
        const int n = P0 + pt;
        const int j = idx[(b * 2048 + n) * 20 + k];
        const float c0 = xb[n], c1 = xb[2048 + n], c2 = xb[4096 + n];
        half8 ev;
        ev[0] = (_Float16)(xb[j] - c0);
        ev[1] = (_Float16)(xb[2048 + j] - c1);
        ev[2] = (_Float16)(xb[4096 + j] - c2);
        ev[3] = (_Float16)c0; ev[4] = (_Float16)c1; ev[5] = (_Float16)c2;
        ev[6] = (_Float16)0.f; ev[7] = (_Float16)0.f;
        ew[el] = ev;
    }

    // ---- y-stage via MFMA: y_raw = e @ W0^T, bn0+leaky, swizzled scatter --
    const half8* w0f8 = (const half8*)w0f;
    const half8 z8 = h8zero();
    half8 B1[4];
    float s0v[4], b0v[4];
#pragma unroll
    for (int nt = 0; nt < 4; ++nt) {
        const half8 v = w0f8[nt * 16 + c];
        B1[nt] = (q == 0) ? v : z8;
        s0v[nt] = bn0s[16 * nt + c];
        b0v[nt] = bn0b[16 * nt + c];
    }
#pragma unroll
    for (int mt = 0; mt < 5; ++mt) {
        const half8 ev = ew[16 * mt + c];
        const half8 Ae = (q == 0) ? ev : z8;
        const int ebase = 16 * mt + 4 * q;
#pragma unroll
        for (int nt = 0; nt < 4; ++nt) {
            f32x4 D = {0.f, 0.f, 0.f, 0.f};
            D = __builtin_amdgcn_mfma_f32_16x16x32_f16(Ae, B1[nt], D, 0, 0, 0);
#pragma unroll
            for (int r = 0; r < 4; ++r) {
                float v = D[r] * s0v[nt] + b0v[nt];
                v = fmaxf(v, NEGSLOPE * v);
                const int edge = ebase + r;
                yw[edge * YSTRIDE + ((16 * nt + c) ^ (edge & 0x38))] =
                    (_Float16)v;
            }
        }
    }

    // ---- GEMM2: K=384; B from this XCD's w1g replica ----
    const half8* w1g8 = (const half8*)w1g + (blockIdx.x & 7) * 3072;

    f32x4 acc[5][4];  // [m][t4], u = 16*t4 + c, edge row = 4q + r
#pragma unroll
    for (int mm = 0; mm < 5; ++mm)
#pragma unroll
        for (int t4 = 0; t4 < 4; ++t4) acc[mm][t4] = (f32x4){0.f, 0.f, 0.f, 0.f};

#pragma unroll 1
    for (int i6 = 0; i6 < 6; ++i6) {
        _Float16 es[5];
#pragma unroll
        for (int mm = 0; mm < 5; ++mm)
            es[mm] = ((const _Float16*)(ew + 16 * mm + c))[i6];
#pragma unroll
        for (int ks2 = 0; ks2 < 2; ++ks2) {
            const int ks = 2 * i6 + ks2;
            half8 B[4];
#pragma unroll
            for (int t4 = 0; t4 < 4; ++t4)
                B[t4] = w1g8[(ks * 4 + t4) * 64 + lane];
#pragma unroll
            for (int mm = 0; mm < 5; ++mm) {
                const int rrow = 16 * mm + c;
                const half8 Af = *(const half8*)&yw[rrow * YSTRIDE +
                                                    ((32 * ks2 + 8 * q) ^ (rrow & 0x38))];
                const half8 An = Af * es[mm];
#pragma unroll
                for (int t4 = 0; t4 < 4; ++t4)
                    acc[mm][t4] = __builtin_amdgcn_mfma_f32_16x16x32_f16(
                        An, B[t4], acc[mm][t4], 0, 0, 0);
            }
        }
    }

    // ---- bn1 + leaky + max over k (k = 4m+q) ----
    float bs1[4], bb1[4];
#pragma unroll
    for (int t4 = 0; t4 < 4; ++t4) {
        bs1[t4] = bn1s[16 * t4 + c];
        bb1[t4] = bn1b[16 * t4 + c];
    }

    float x1[4][4];  // [pt r][t4]
#pragma unroll
    for (int r = 0; r < 4; ++r)
#pragma unroll
        for (int t4 = 0; t4 < 4; ++t4) {
            float v = NINF;
#pragma unroll
            for (int mm = 0; mm < 5; ++mm) {
                float w = acc[mm][t4][r] * bs1[t4] + bb1[t4];
                w = fmaxf(w, NEGSLOPE * w);
                v = fmaxf(v, w);
            }
            v = fmaxf(v, __shfl_xor(v, 16, 64));
            v = fmaxf(v, __shfl_xor(v, 32, 64));
            x1[r][t4] = v;
        }

    // ---- head: z[pt][co] = leaky(bnc(sum_u x1*wc)) ----
    float wcv[3][4];
#pragma unroll
    for (int co = 0; co < 3; ++co)
#pragma unroll
        for (int t4 = 0; t4 < 4; ++t4) wcv[co][t4] = wc[co * 64 + 16 * t4 + c];

    float part[4][3];
#pragma unroll
    for (int r = 0; r < 4; ++r)
#pragma unroll
        for (int co = 0; co < 3; ++co) {
            float s = x1[r][0] * wcv[co][0] + x1[r][1] * wcv[co][1] +
                      x1[r][2] * wcv[co][2] + x1[r][3] * wcv[co][3];
#pragma unroll
            for (int d = 1; d < 16; d <<= 1) s += __shfl_xor(s, d, 64);
            part[r][co] = s;
        }

    if (c == 0 && q < 3) {
        const float sc = bncs[q], bc = bncb[q];
#pragma unroll
        for (int r = 0; r < 4; ++r) {
            float z = part[r][q] * sc + bc;
            z = fmaxf(z, NEGSLOPE * z);
            out[(b * 3 + q) * 2048 + P0 + r] = z;
        }
    }
}

// ---------------------------------------------------------------------------
extern "C" void kernel_launch(void* const* d_in, const int* in_sizes, int n_in,
                              void* d_out, int out_size, void* d_ws, size_t ws_size,
                              hipStream_t stream) {
    const float* x    = (const float*)d_in[0];
    const float* W0   = (const float*)d_in[1];
    const float* bn0s = (const float*)d_in[2];
    const float* bn0b = (const float*)d_in[3];
    const float* W1   = (const float*)d_in[4];
    const float* bn1s = (const float*)d_in[5];
    const float* bn1b = (const float*)d_in[6];
    const float* Wc   = (const float*)d_in[7];
    const float* bncs = (const float*)d_in[8];
    const float* bncb = (const float*)d_in[9];

    _Float16* w1g = (_Float16*)d_ws;                     // 8 x 48 KiB @ 0
    _Float16* w0f = (_Float16*)((char*)d_ws + 393216);   // 1 KiB
    int* idx = (int*)((char*)d_ws + 458752);             // 1.25 MiB

    topk_kernel<<<4104, 256, 0, stream>>>(x, idx, W1, w1g, W0, w0f);
    mlp_mfma<<<2048, 128, 0, stream>>>(x, idx, w0f, bn0s, bn0b, w1g,
                                       bn1s, bn1b, Wc, bncs, bncb,
                                       (float*)d_out);
}